// Round 1
// baseline (2189.449 us; speedup 1.0000x reference)
//
#include <hip/hip_runtime.h>
#include <math.h>

#define N_ATOMS 50000
#define N_EDGES 1600000
#define NF 128
#define NG 50
#define LOG2F_ 0.69314718055994530942f
#define PI_OVER_CUT 0.31415926535897932f
#define CUTOFF_F 10.0f

__device__ __forceinline__ float sspf(float x) {
    // softplus(x) - log(2), numerically stable
    float ax = fabsf(x);
    return fmaxf(x, 0.0f) + log1pf(__expf(-ax)) - LOG2F_;
}

// Y[N][128] = X[N][128] @ W[128][128]  (+ bias, ssp if BIAS_SSP)
template <bool BIAS_SSP>
__global__ __launch_bounds__(256) void gemm128_kernel(
    const float* __restrict__ X, const float* __restrict__ W,
    const float* __restrict__ bias, float* __restrict__ Y, int N) {
    __shared__ float xs[32][128];
    const int row0 = blockIdx.x * 32;
    const int tid = threadIdx.x;

    // load X tile (guarded): 32 rows x 32 float4
    {
        const float4* src = (const float4*)(X + (size_t)row0 * 128);
        float4* dst = (float4*)(&xs[0][0]);
        for (int i = tid; i < 32 * 32; i += 256) {
            int r = i >> 5;
            float4 v = {0.f, 0.f, 0.f, 0.f};
            if (row0 + r < N) v = src[i];
            dst[i] = v;
        }
    }
    __syncthreads();

    const int rq = tid >> 5;   // row quad 0..7
    const int cq = tid & 31;   // col quad 0..31
    float4 a0 = {0,0,0,0}, a1 = {0,0,0,0}, a2 = {0,0,0,0}, a3 = {0,0,0,0};
    const float4* Wv = (const float4*)W;

    #pragma unroll 4
    for (int k = 0; k < 128; ++k) {
        float4 w = Wv[k * 32 + cq];
        float x0 = xs[rq * 4 + 0][k];
        float x1 = xs[rq * 4 + 1][k];
        float x2 = xs[rq * 4 + 2][k];
        float x3 = xs[rq * 4 + 3][k];
        a0.x += x0 * w.x; a0.y += x0 * w.y; a0.z += x0 * w.z; a0.w += x0 * w.w;
        a1.x += x1 * w.x; a1.y += x1 * w.y; a1.z += x1 * w.z; a1.w += x1 * w.w;
        a2.x += x2 * w.x; a2.y += x2 * w.y; a2.z += x2 * w.z; a2.w += x2 * w.w;
        a3.x += x3 * w.x; a3.y += x3 * w.y; a3.z += x3 * w.z; a3.w += x3 * w.w;
    }

    float4 bq = {0,0,0,0};
    if (BIAS_SSP) bq = ((const float4*)bias)[cq];
    float4 accs[1];
    #pragma unroll
    for (int i = 0; i < 4; ++i) {
        float4 v = (i == 0) ? a0 : (i == 1) ? a1 : (i == 2) ? a2 : a3;
        int r = row0 + rq * 4 + i;
        if (r >= N) continue;
        if (BIAS_SSP) {
            v.x = sspf(v.x + bq.x); v.y = sspf(v.y + bq.y);
            v.z = sspf(v.z + bq.z); v.w = sspf(v.w + bq.w);
        }
        ((float4*)(Y + (size_t)r * 128))[cq] = v;
        (void)accs;
    }
}

// Fused edge kernel: 32 edges per block.
// W1 = ssp(f@Wf1+b1); W2 = ssp(W1@Wf2+b2)*C; atomicAdd(agg[ind_i], h[ind_j]*W2)
__global__ __launch_bounds__(256) void edge_kernel(
    const float* __restrict__ f_ij, const float* __restrict__ r_ij,
    const int* __restrict__ ind_i, const int* __restrict__ ind_j,
    const float* __restrict__ Wf1, const float* __restrict__ bf1,
    const float* __restrict__ Wf2, const float* __restrict__ bf2,
    const float* __restrict__ h, float* __restrict__ agg) {
    __shared__ float fs[32][52];       // padded
    __shared__ float w1[32][128];
    __shared__ float w2[32][128];
    __shared__ float cc[32];
    __shared__ int js[32], is_[32];

    const int e0 = blockIdx.x * 32;
    const int tid = threadIdx.x;

    // load f tile [32][50]
    for (int i = tid; i < 32 * NG; i += 256) {
        int e = i / NG, g = i - e * NG;
        fs[e][g] = f_ij[(size_t)e0 * NG + i];
    }
    if (tid < 32) {
        float r = r_ij[e0 + tid];
        float c = 0.5f * (cosf(r * PI_OVER_CUT) + 1.0f);
        cc[tid] = (r < CUTOFF_F) ? c : 0.0f;
        js[tid] = ind_j[e0 + tid];
        is_[tid] = ind_i[e0 + tid];
    }
    __syncthreads();

    const int eq = tid >> 5;   // edge quad 0..7
    const int cq = tid & 31;   // col quad 0..31

    // ---- GEMM1: [32][50] @ [50][128] ----
    {
        float4 a0 = {0,0,0,0}, a1 = {0,0,0,0}, a2 = {0,0,0,0}, a3 = {0,0,0,0};
        const float4* Wv = (const float4*)Wf1;
        #pragma unroll 5
        for (int k = 0; k < NG; ++k) {
            float4 w = Wv[k * 32 + cq];
            float x0 = fs[eq * 4 + 0][k];
            float x1 = fs[eq * 4 + 1][k];
            float x2 = fs[eq * 4 + 2][k];
            float x3 = fs[eq * 4 + 3][k];
            a0.x += x0 * w.x; a0.y += x0 * w.y; a0.z += x0 * w.z; a0.w += x0 * w.w;
            a1.x += x1 * w.x; a1.y += x1 * w.y; a1.z += x1 * w.z; a1.w += x1 * w.w;
            a2.x += x2 * w.x; a2.y += x2 * w.y; a2.z += x2 * w.z; a2.w += x2 * w.w;
            a3.x += x3 * w.x; a3.y += x3 * w.y; a3.z += x3 * w.z; a3.w += x3 * w.w;
        }
        float4 b1 = ((const float4*)bf1)[cq];
        #pragma unroll
        for (int i = 0; i < 4; ++i) {
            float4 v = (i == 0) ? a0 : (i == 1) ? a1 : (i == 2) ? a2 : a3;
            v.x = sspf(v.x + b1.x); v.y = sspf(v.y + b1.y);
            v.z = sspf(v.z + b1.z); v.w = sspf(v.w + b1.w);
            ((float4*)(&w1[eq * 4 + i][0]))[cq] = v;
        }
    }
    __syncthreads();

    // ---- GEMM2: [32][128] @ [128][128] ----
    {
        float4 a0 = {0,0,0,0}, a1 = {0,0,0,0}, a2 = {0,0,0,0}, a3 = {0,0,0,0};
        const float4* Wv = (const float4*)Wf2;
        #pragma unroll 4
        for (int k = 0; k < 128; ++k) {
            float4 w = Wv[k * 32 + cq];
            float x0 = w1[eq * 4 + 0][k];
            float x1 = w1[eq * 4 + 1][k];
            float x2 = w1[eq * 4 + 2][k];
            float x3 = w1[eq * 4 + 3][k];
            a0.x += x0 * w.x; a0.y += x0 * w.y; a0.z += x0 * w.z; a0.w += x0 * w.w;
            a1.x += x1 * w.x; a1.y += x1 * w.y; a1.z += x1 * w.z; a1.w += x1 * w.w;
            a2.x += x2 * w.x; a2.y += x2 * w.y; a2.z += x2 * w.z; a2.w += x2 * w.w;
            a3.x += x3 * w.x; a3.y += x3 * w.y; a3.z += x3 * w.z; a3.w += x3 * w.w;
        }
        float4 b2 = ((const float4*)bf2)[cq];
        #pragma unroll
        for (int i = 0; i < 4; ++i) {
            float4 v = (i == 0) ? a0 : (i == 1) ? a1 : (i == 2) ? a2 : a3;
            int e = eq * 4 + i;
            float c = cc[e];
            v.x = sspf(v.x + b2.x) * c; v.y = sspf(v.y + b2.y) * c;
            v.z = sspf(v.z + b2.z) * c; v.w = sspf(v.w + b2.w) * c;
            ((float4*)(&w2[e][0]))[cq] = v;
        }
    }
    __syncthreads();

    // ---- gather h[j], scatter-add agg[i] ----
    for (int idx = tid; idx < 32 * 128; idx += 256) {
        int e = idx >> 7, c = idx & 127;
        int j = js[e], i = is_[e];
        float m = h[(size_t)j * 128 + c] * w2[e][c];
        atomicAdd(&agg[(size_t)i * 128 + c], m);
    }
}

extern "C" void kernel_launch(void* const* d_in, const int* in_sizes, int n_in,
                              void* d_out, int out_size, void* d_ws, size_t ws_size,
                              hipStream_t stream) {
    const float* x    = (const float*)d_in[0];
    const float* r_ij = (const float*)d_in[1];
    const float* f_ij = (const float*)d_in[2];
    const int*   ind_i = (const int*)d_in[3];
    const int*   ind_j = (const int*)d_in[4];
    const float* Wf1  = (const float*)d_in[5];
    const float* bf1  = (const float*)d_in[6];
    const float* Wf2  = (const float*)d_in[7];
    const float* bf2  = (const float*)d_in[8];
    const float* Win  = (const float*)d_in[9];
    const float* Wout = (const float*)d_in[10];
    const float* bout = (const float*)d_in[11];
    float* out = (float*)d_out;

    float* agg = (float*)d_ws;                       // [N_ATOMS][128]
    float* h   = agg + (size_t)N_ATOMS * NF;         // [N_ATOMS][128]

    hipMemsetAsync(agg, 0, (size_t)N_ATOMS * NF * sizeof(float), stream);

    const int gemm_blocks = (N_ATOMS + 31) / 32;
    gemm128_kernel<false><<<gemm_blocks, 256, 0, stream>>>(x, Win, nullptr, h, N_ATOMS);
    edge_kernel<<<N_EDGES / 32, 256, 0, stream>>>(f_ij, r_ij, ind_i, ind_j,
                                                  Wf1, bf1, Wf2, bf2, h, agg);
    gemm128_kernel<true><<<gemm_blocks, 256, 0, stream>>>(agg, Wout, bout, out, N_ATOMS);
}

// Round 2
// 1623.945 us; speedup vs baseline: 1.3482x; 1.3482x over previous
//
#include <hip/hip_runtime.h>
#include <math.h>

#define N_ATOMS 50000
#define N_EDGES 1600000
#define NF 128
#define NG 50
#define LOG2F_ 0.69314718055994530942f
#define PI_OVER_CUT 0.31415926535897932f
#define CUTOFF_F 10.0f

typedef _Float16 half_t;
typedef _Float16 f16x8 __attribute__((ext_vector_type(8)));
typedef float f32x4 __attribute__((ext_vector_type(4)));
typedef unsigned int u32x4 __attribute__((ext_vector_type(4)));

__device__ __forceinline__ float sspf(float x) {
    float ax = fabsf(x);
    return fmaxf(x, 0.0f) + log1pf(__expf(-ax)) - LOG2F_;
}

__device__ __forceinline__ unsigned short f2h_bits(float x) {
    half_t h = (half_t)x;
    return __builtin_bit_cast(unsigned short, h);
}

// ---------------- fp32 node GEMM (unchanged, works) ----------------
template <bool BIAS_SSP>
__global__ __launch_bounds__(256) void gemm128_kernel(
    const float* __restrict__ X, const float* __restrict__ W,
    const float* __restrict__ bias, float* __restrict__ Y, int N) {
    __shared__ float xs[32][128];
    const int row0 = blockIdx.x * 32;
    const int tid = threadIdx.x;
    {
        const float4* src = (const float4*)(X + (size_t)row0 * 128);
        float4* dst = (float4*)(&xs[0][0]);
        for (int i = tid; i < 32 * 32; i += 256) {
            int r = i >> 5;
            float4 v = {0.f, 0.f, 0.f, 0.f};
            if (row0 + r < N) v = src[i];
            dst[i] = v;
        }
    }
    __syncthreads();

    const int rq = tid >> 5;
    const int cq = tid & 31;
    float4 a0 = {0,0,0,0}, a1 = {0,0,0,0}, a2 = {0,0,0,0}, a3 = {0,0,0,0};
    const float4* Wv = (const float4*)W;

    #pragma unroll 4
    for (int k = 0; k < 128; ++k) {
        float4 w = Wv[k * 32 + cq];
        float x0 = xs[rq * 4 + 0][k];
        float x1 = xs[rq * 4 + 1][k];
        float x2 = xs[rq * 4 + 2][k];
        float x3 = xs[rq * 4 + 3][k];
        a0.x += x0 * w.x; a0.y += x0 * w.y; a0.z += x0 * w.z; a0.w += x0 * w.w;
        a1.x += x1 * w.x; a1.y += x1 * w.y; a1.z += x1 * w.z; a1.w += x1 * w.w;
        a2.x += x2 * w.x; a2.y += x2 * w.y; a2.z += x2 * w.z; a2.w += x2 * w.w;
        a3.x += x3 * w.x; a3.y += x3 * w.y; a3.z += x3 * w.z; a3.w += x3 * w.w;
    }

    float4 bq = {0,0,0,0};
    if (BIAS_SSP) bq = ((const float4*)bias)[cq];
    #pragma unroll
    for (int i = 0; i < 4; ++i) {
        float4 v = (i == 0) ? a0 : (i == 1) ? a1 : (i == 2) ? a2 : a3;
        int r = row0 + rq * 4 + i;
        if (r >= N) continue;
        if (BIAS_SSP) {
            v.x = sspf(v.x + bq.x); v.y = sspf(v.y + bq.y);
            v.z = sspf(v.z + bq.z); v.w = sspf(v.w + bq.w);
        }
        ((float4*)(Y + (size_t)r * 128))[cq] = v;
    }
}

// ---------------- weight pre-convert: f32 -> f16, transposed ----------------
// w1t[col][k] (128x64, k>=50 zero-padded), w2t[col][k] (128x128)
__global__ __launch_bounds__(256) void preconv_kernel(
    const float* __restrict__ Wf1, const float* __restrict__ Wf2,
    half_t* __restrict__ w1t, half_t* __restrict__ w2t) {
    int id = blockIdx.x * 256 + threadIdx.x;
    if (id < 128 * 64) {
        int col = id >> 6, k = id & 63;
        w1t[id] = (k < NG) ? (half_t)Wf1[k * NF + col] : (half_t)0.0f;
    } else if (id < 128 * 64 + 128 * 128) {
        int t = id - 128 * 64;
        int col = t >> 7, k = t & 127;
        w2t[t] = (half_t)Wf2[k * NF + col];
    }
}

// ---------------- LDS layout (bytes) ----------------
#define OFF_FA    0        // [64][64] f16, swizzled, 8192 B   (GEMM1 A)
#define OFF_W1T   8192     // [128][64] f16, swizzled, 16384 B (GEMM1 B)
#define OFF_W1OUT 0        // [4 waves][16][128] f16, swizzled, 16384 B (reuses FA/W1T)
#define OFF_W2T   24576    // [128][128] f16, swizzled, 32768 B (GEMM2 B)
#define OFF_CC    57344
#define OFF_JS    57600
#define OFF_IS    57856
#define OFF_B1    58112
#define OFF_B2    58624
#define LDS_BYTES 59136

// ---------------- fused edge kernel: 64 edges/block, 4 waves ----------------
__global__ __launch_bounds__(256) void edge_kernel(
    const float* __restrict__ f_ij, const float* __restrict__ r_ij,
    const int* __restrict__ ind_i, const int* __restrict__ ind_j,
    const half_t* __restrict__ w1t_g, const half_t* __restrict__ w2t_g,
    const float* __restrict__ bf1, const float* __restrict__ bf2,
    const float* __restrict__ h, float* __restrict__ agg) {
    __shared__ __align__(16) unsigned char lds[LDS_BYTES];

    const int tid = threadIdx.x;
    const int e0 = blockIdx.x * 64;

    // ---- stage f tile: [64 edges][64 k] f16 (k>=50 zero), swizzled ----
    for (int idx = tid; idx < 64 * 32; idx += 256) {
        int e = idx >> 5, p = idx & 31, k = p * 2;
        float2 v = {0.f, 0.f};
        if (k < NG) v = *(const float2*)(f_ij + (size_t)(e0 + e) * NG + k);
        unsigned int pack = (unsigned int)f2h_bits(v.x) | ((unsigned int)f2h_bits(v.y) << 16);
        int byte = e * 128 + (((k >> 3) ^ (e & 7)) << 4) + (k & 7) * 2;
        *(unsigned int*)(lds + OFF_FA + byte) = pack;
    }
    // ---- stage W1T: 1024 16B-chunks, swizzle on write ----
    for (int c = tid; c < 128 * 8; c += 256) {
        int col = c >> 3, kc = c & 7;
        u32x4 v = *((const u32x4*)w1t_g + c);
        *(u32x4*)(lds + OFF_W1T + col * 128 + ((kc ^ (col & 7)) << 4)) = v;
    }
    // ---- stage W2T: 2048 16B-chunks, swizzle on write ----
    for (int c = tid; c < 128 * 16; c += 256) {
        int col = c >> 4, kc = c & 15;
        u32x4 v = *((const u32x4*)w2t_g + c);
        *(u32x4*)(lds + OFF_W2T + col * 256 + ((kc ^ (col & 7)) << 4)) = v;
    }
    // ---- stage cutoff / indices / biases ----
    if (tid < 64) {
        float r = r_ij[e0 + tid];
        float c = 0.5f * (cosf(r * PI_OVER_CUT) + 1.0f);
        ((float*)(lds + OFF_CC))[tid] = (r < CUTOFF_F) ? c : 0.0f;
        ((int*)(lds + OFF_JS))[tid] = ind_j[e0 + tid];
        ((int*)(lds + OFF_IS))[tid] = ind_i[e0 + tid];
    }
    if (tid < 128) {
        ((float*)(lds + OFF_B1))[tid] = bf1[tid];
        ((float*)(lds + OFF_B2))[tid] = bf2[tid];
    }
    __syncthreads();

    const int lane = tid & 63;
    const int wid = tid >> 6;
    const int l15 = lane & 15;
    const int lg = lane >> 4;          // lane group 0..3
    const int wbase = wid * 16;        // this wave's edge stripe

    // ---- GEMM1: [16x64] @ [64x128] per wave ----
    f32x4 acc[8];
    #pragma unroll
    for (int t = 0; t < 8; ++t) acc[t] = (f32x4){0.f, 0.f, 0.f, 0.f};

    const int arow = wbase + l15;
    f16x8 a1[2];
    #pragma unroll
    for (int ks = 0; ks < 2; ++ks) {
        int byte = arow * 128 + (((lg + 4 * ks) ^ (arow & 7)) << 4);
        a1[ks] = *(const f16x8*)(lds + OFF_FA + byte);
    }
    #pragma unroll
    for (int t = 0; t < 8; ++t) {
        int col = t * 16 + l15;
        #pragma unroll
        for (int ks = 0; ks < 2; ++ks) {
            int byte = col * 128 + (((lg + 4 * ks) ^ (col & 7)) << 4);
            f16x8 b = *(const f16x8*)(lds + OFF_W1T + byte);
            acc[t] = __builtin_amdgcn_mfma_f32_16x16x32_f16(a1[ks], b, acc[t], 0, 0, 0);
        }
    }
    __syncthreads();   // all waves done reading FA/W1T; region reused for W1OUT

    // ---- epilogue1: bias + ssp -> f16 -> per-wave w1 LDS (swizzled) ----
    const float* b1s = (const float*)(lds + OFF_B1);
    unsigned char* w1w = lds + OFF_W1OUT + wid * 4096;
    #pragma unroll
    for (int t = 0; t < 8; ++t) {
        int col = t * 16 + l15;
        float bb = b1s[col];
        #pragma unroll
        for (int r = 0; r < 4; ++r) {
            int row = lg * 4 + r;
            unsigned short bits = f2h_bits(sspf(acc[t][r] + bb));
            int byte = row * 256 + ((((col >> 3) ^ (row & 7))) << 4) + (col & 7) * 2;
            *(unsigned short*)(w1w + byte) = bits;
        }
    }

    // ---- GEMM2: [16x128] @ [128x128] per wave ----
    f32x4 acc2[8];
    #pragma unroll
    for (int t = 0; t < 8; ++t) acc2[t] = (f32x4){0.f, 0.f, 0.f, 0.f};

    f16x8 a2[4];
    #pragma unroll
    for (int ks = 0; ks < 4; ++ks) {
        int byte = l15 * 256 + (((lg + 4 * ks) ^ (l15 & 7)) << 4);
        a2[ks] = *(const f16x8*)(w1w + byte);
    }
    #pragma unroll
    for (int t = 0; t < 8; ++t) {
        int col = t * 16 + l15;
        #pragma unroll
        for (int ks = 0; ks < 4; ++ks) {
            int byte = col * 256 + (((lg + 4 * ks) ^ (col & 7)) << 4);
            f16x8 b = *(const f16x8*)(lds + OFF_W2T + byte);
            acc2[t] = __builtin_amdgcn_mfma_f32_16x16x32_f16(a2[ks], b, acc2[t], 0, 0, 0);
        }
    }

    // ---- epilogue2: ssp * cutoff, gather h[j], scatter-add agg[i] ----
    const float* b2s = (const float*)(lds + OFF_B2);
    const float* ccs = (const float*)(lds + OFF_CC);
    const int* jss = (const int*)(lds + OFF_JS);
    const int* iss = (const int*)(lds + OFF_IS);
    #pragma unroll
    for (int r = 0; r < 4; ++r) {
        int row = lg * 4 + r;
        int ge = wbase + row;
        float ccv = ccs[ge];
        int j = jss[ge], ii = iss[ge];
        const float* hrow = h + (size_t)j * NF;
        float* grow = agg + (size_t)ii * NF;
        #pragma unroll
        for (int t = 0; t < 8; ++t) {
            int col = t * 16 + l15;
            float w2v = sspf(acc2[t][r] + b2s[col]) * ccv;
            atomicAdd(grow + col, hrow[col] * w2v);
        }
    }
}

extern "C" void kernel_launch(void* const* d_in, const int* in_sizes, int n_in,
                              void* d_out, int out_size, void* d_ws, size_t ws_size,
                              hipStream_t stream) {
    const float* x     = (const float*)d_in[0];
    const float* r_ij  = (const float*)d_in[1];
    const float* f_ij  = (const float*)d_in[2];
    const int*   ind_i = (const int*)d_in[3];
    const int*   ind_j = (const int*)d_in[4];
    const float* Wf1   = (const float*)d_in[5];
    const float* bf1   = (const float*)d_in[6];
    const float* Wf2   = (const float*)d_in[7];
    const float* bf2   = (const float*)d_in[8];
    const float* Win   = (const float*)d_in[9];
    const float* Wout  = (const float*)d_in[10];
    const float* bout  = (const float*)d_in[11];
    float* out = (float*)d_out;

    float*  agg  = (float*)d_ws;                          // [N][128] f32
    float*  h    = agg + (size_t)N_ATOMS * NF;            // [N][128] f32
    half_t* w1t  = (half_t*)(h + (size_t)N_ATOMS * NF);   // [128][64] f16
    half_t* w2t  = w1t + 128 * 64;                        // [128][128] f16

    hipMemsetAsync(agg, 0, (size_t)N_ATOMS * NF * sizeof(float), stream);

    preconv_kernel<<<96, 256, 0, stream>>>(Wf1, Wf2, w1t, w2t);

    const int gemm_blocks = (N_ATOMS + 31) / 32;
    gemm128_kernel<false><<<gemm_blocks, 256, 0, stream>>>(x, Win, nullptr, h, N_ATOMS);

    edge_kernel<<<N_EDGES / 64, 256, 0, stream>>>(f_ij, r_ij, ind_i, ind_j,
                                                  w1t, w2t, bf1, bf2, h, agg);

    gemm128_kernel<true><<<gemm_blocks, 256, 0, stream>>>(agg, Wout, bout, out, N_ATOMS);
}

// Round 4
// 1010.483 us; speedup vs baseline: 2.1667x; 1.6071x over previous
//
#include <hip/hip_runtime.h>
#include <math.h>

#define N_ATOMS 50000
#define N_EDGES 1600000
#define NF 128
#define NG 50
#define ITERS 8
#define EPB (64 * ITERS)   // 512 edges per block
#define LOG2F_ 0.69314718055994530942f
#define PI_OVER_CUT 0.31415926535897932f
#define CUTOFF_F 10.0f

typedef _Float16 half_t;
typedef _Float16 f16x8 __attribute__((ext_vector_type(8)));
typedef _Float16 f16x2 __attribute__((ext_vector_type(2)));
typedef float f32x4 __attribute__((ext_vector_type(4)));
typedef unsigned int u32x4 __attribute__((ext_vector_type(4)));

__device__ __forceinline__ float sspf_fast(float x) {
    // softplus(x) - log2, ~6 VALU ops via v_exp/v_log
    float e = __expf(-fabsf(x));
    float l = __logf(1.0f + e);
    return fmaxf(x, 0.0f) + (l - LOG2F_);
}

__device__ __forceinline__ unsigned short f2h_bits(float x) {
    half_t h = (half_t)x;
    return __builtin_bit_cast(unsigned short, h);
}

// ---------------- fp32 node GEMM (unchanged) ----------------
template <bool BIAS_SSP>
__global__ __launch_bounds__(256) void gemm128_kernel(
    const float* __restrict__ X, const float* __restrict__ W,
    const float* __restrict__ bias, float* __restrict__ Y, int N) {
    __shared__ float xs[32][128];
    const int row0 = blockIdx.x * 32;
    const int tid = threadIdx.x;
    {
        const float4* src = (const float4*)(X + (size_t)row0 * 128);
        float4* dst = (float4*)(&xs[0][0]);
        for (int i = tid; i < 32 * 32; i += 256) {
            int r = i >> 5;
            float4 v = {0.f, 0.f, 0.f, 0.f};
            if (row0 + r < N) v = src[i];
            dst[i] = v;
        }
    }
    __syncthreads();

    const int rq = tid >> 5;
    const int cq = tid & 31;
    float4 a0 = {0,0,0,0}, a1 = {0,0,0,0}, a2 = {0,0,0,0}, a3 = {0,0,0,0};
    const float4* Wv = (const float4*)W;

    #pragma unroll 4
    for (int k = 0; k < 128; ++k) {
        float4 w = Wv[k * 32 + cq];
        float x0 = xs[rq * 4 + 0][k];
        float x1 = xs[rq * 4 + 1][k];
        float x2 = xs[rq * 4 + 2][k];
        float x3 = xs[rq * 4 + 3][k];
        a0.x += x0 * w.x; a0.y += x0 * w.y; a0.z += x0 * w.z; a0.w += x0 * w.w;
        a1.x += x1 * w.x; a1.y += x1 * w.y; a1.z += x1 * w.z; a1.w += x1 * w.w;
        a2.x += x2 * w.x; a2.y += x2 * w.y; a2.z += x2 * w.z; a2.w += x2 * w.w;
        a3.x += x3 * w.x; a3.y += x3 * w.y; a3.z += x3 * w.z; a3.w += x3 * w.w;
    }

    float4 bq = {0,0,0,0};
    if (BIAS_SSP) bq = ((const float4*)bias)[cq];
    #pragma unroll
    for (int i = 0; i < 4; ++i) {
        float4 v = (i == 0) ? a0 : (i == 1) ? a1 : (i == 2) ? a2 : a3;
        int r = row0 + rq * 4 + i;
        if (r >= N) continue;
        if (BIAS_SSP) {
            v.x = sspf_fast(v.x + bq.x); v.y = sspf_fast(v.y + bq.y);
            v.z = sspf_fast(v.z + bq.z); v.w = sspf_fast(v.w + bq.w);
        }
        ((float4*)(Y + (size_t)r * 128))[cq] = v;
    }
}

// ---------------- weight pre-convert: f32 -> f16, transposed ----------------
__global__ __launch_bounds__(256) void preconv_kernel(
    const float* __restrict__ Wf1, const float* __restrict__ Wf2,
    half_t* __restrict__ w1t, half_t* __restrict__ w2t) {
    int id = blockIdx.x * 256 + threadIdx.x;
    if (id < 128 * 64) {
        int col = id >> 6, k = id & 63;
        w1t[id] = (k < NG) ? (half_t)Wf1[k * NF + col] : (half_t)0.0f;
    } else if (id < 128 * 64 + 128 * 128) {
        int t = id - 128 * 64;
        int col = t >> 7, k = t & 127;
        w2t[t] = (half_t)Wf2[k * NF + col];
    }
}

// LDS: [0,16384) W1T [col][64k] swz | [16384,49152) W2T [col][128k] swz
//      [49152,65536) per-wave W1OUT [16][128] swz (4 KB each)
#define OFF_W2T   16384
#define OFF_W1OUT 49152

__global__ __launch_bounds__(256) void edge_kernel(
    const float* __restrict__ f_ij, const float* __restrict__ r_ij,
    const int* __restrict__ ind_i, const int* __restrict__ ind_j,
    const half_t* __restrict__ w1t_g, const half_t* __restrict__ w2t_g,
    const float* __restrict__ bf1, const float* __restrict__ bf2,
    const float* __restrict__ h, float* __restrict__ agg) {
    __shared__ __align__(16) unsigned char lds[65536];
    const int tid = threadIdx.x;

    // ---- stage weights once per block ----
    for (int c = tid; c < 1024; c += 256) {
        int col = c >> 3, kc = c & 7;
        u32x4 v = ((const u32x4*)w1t_g)[c];
        *(u32x4*)(lds + (col << 7) + ((kc ^ (col & 7)) << 4)) = v;
    }
    for (int c = tid; c < 2048; c += 256) {
        int col = c >> 4, kc = c & 15;
        u32x4 v = ((const u32x4*)w2t_g)[c];
        int slot = (kc & 8) | ((kc & 7) ^ (col & 7));
        *(u32x4*)(lds + OFF_W2T + (col << 8) + (slot << 4)) = v;
    }

    const int lane = tid & 63;
    const int wid = tid >> 6;
    const int l15 = lane & 15;
    const int lg  = lane >> 4;
    const int l7  = lane & 7;
    const int h3  = l15 >> 3;
    const int hb  = (l7 >> 2) & 1;
    const int lgl = lg ^ (l7 & 3);

    float b1r[8], b2r[8];
    #pragma unroll
    for (int t = 0; t < 8; ++t) {
        b1r[t] = bf1[t * 16 + l15];
        b2r[t] = bf2[t * 16 + l15];
    }

    // per-lane constant LDS bases (swizzle algebra: (t*16+l15)&7 == l15&7)
    const int b1b0 = (l15 << 7) + (hb << 6) + (lgl << 4);
    const int b1b1 = (l15 << 7) + ((hb ^ 1) << 6) + (lgl << 4);
    const int b2b0 = OFF_W2T + (l15 << 8) + (hb << 6) + (lgl << 4);
    const int b2b1 = OFF_W2T + (l15 << 8) + ((hb ^ 1) << 6) + (lgl << 4);
    const int a2b0 = OFF_W1OUT + wid * 4096 + (l15 << 8) + (hb << 6) + (lgl << 4);
    const int a2b1 = OFF_W1OUT + wid * 4096 + (l15 << 8) + ((hb ^ 1) << 6) + (lgl << 4);
    const int ep1base = OFF_W1OUT + wid * 4096 + lg * 1024 + l7 * 2;
    const int rw4 = (lg & 1) * 4;

    const int bb = blockIdx.x * EPB;
    const float* aptr = f_ij + (size_t)(bb + wid * 16 + l15) * NG + lg * 8;

    __syncthreads();

    for (int it = 0; it < ITERS; ++it) {
        const int eb = bb + it * 64 + wid * 16;

        // ---- A fragments: global -> registers (rows are lane-local) ----
        float2 q[8];
        #pragma unroll
        for (int p = 0; p < 4; ++p) q[p] = *(const float2*)(aptr + 2 * p);
        #pragma unroll
        for (int p = 0; p < 4; ++p) {
            float2 v = {0.f, 0.f};
            if (lg * 8 + 2 * p <= 16) v = *(const float2*)(aptr + 32 + 2 * p);
            q[4 + p] = v;
        }
        f16x8 a1[2];
        #pragma unroll
        for (int ks = 0; ks < 2; ++ks) {
            #pragma unroll
            for (int p = 0; p < 4; ++p) {
                f16x2 hv = __builtin_bit_cast(f16x2,
                    __builtin_amdgcn_cvt_pkrtz(q[ks * 4 + p].x, q[ks * 4 + p].y));
                a1[ks][2 * p]     = hv[0];
                a1[ks][2 * p + 1] = hv[1];
            }
        }
        aptr += (size_t)64 * NG;

        // ---- GEMM1: [16x64] @ [64x128] ----
        f32x4 acc1[8];
        #pragma unroll
        for (int t = 0; t < 8; ++t) acc1[t] = (f32x4){0.f, 0.f, 0.f, 0.f};
        #pragma unroll
        for (int t = 0; t < 8; ++t) {
            f16x8 b0 = *(const f16x8*)(lds + b1b0 + t * 2048);
            f16x8 b1 = *(const f16x8*)(lds + b1b1 + t * 2048);
            acc1[t] = __builtin_amdgcn_mfma_f32_16x16x32_f16(a1[0], b0, acc1[t], 0, 0, 0);
            acc1[t] = __builtin_amdgcn_mfma_f32_16x16x32_f16(a1[1], b1, acc1[t], 0, 0, 0);
        }

        // ---- epilogue1: ssp -> f16 -> per-wave W1OUT (swizzled) ----
        #pragma unroll
        for (int t = 0; t < 8; ++t) {
            #pragma unroll
            for (int r = 0; r < 4; ++r) {
                unsigned short bits = f2h_bits(sspf_fast(acc1[t][r] + b1r[t]));
                int slotx = (2 * (t & 3) + h3) ^ (rw4 + r);
                *(unsigned short*)(lds + ep1base + r * 256 + ((t >> 2) << 7) + (slotx << 4)) = bits;
            }
        }

        // ---- GEMM2: [16x128] @ [128x128] ----
        f32x4 acc2[8];
        #pragma unroll
        for (int t = 0; t < 8; ++t) acc2[t] = (f32x4){0.f, 0.f, 0.f, 0.f};
        f16x8 a2[4];
        #pragma unroll
        for (int ks = 0; ks < 4; ++ks) {
            int addr = ((ks & 1) ? a2b1 : a2b0) + (ks >> 1) * 128;
            a2[ks] = *(const f16x8*)(lds + addr);
        }
        #pragma unroll
        for (int t = 0; t < 8; ++t) {
            #pragma unroll
            for (int ks = 0; ks < 4; ++ks) {
                int addr = ((ks & 1) ? b2b1 : b2b0) + (ks >> 1) * 128 + t * 4096;
                f16x8 b = *(const f16x8*)(lds + addr);
                acc2[t] = __builtin_amdgcn_mfma_f32_16x16x32_f16(a2[ks], b, acc2[t], 0, 0, 0);
            }
        }

        // ---- epilogue2: ssp*cutoff, gather h[j], scatter-add agg[i] ----
        const int erow = eb + lg * 4;
        float rv[4]; int jv[4], iv[4];
        #pragma unroll
        for (int r = 0; r < 4; ++r) {
            rv[r] = r_ij[erow + r];
            jv[r] = ind_j[erow + r];
            iv[r] = ind_i[erow + r];
        }
        #pragma unroll
        for (int r = 0; r < 4; ++r) {
            float c = 0.5f * (__cosf(rv[r] * PI_OVER_CUT) + 1.0f);
            c = (rv[r] < CUTOFF_F) ? c : 0.0f;
            const float* hrow = h + (size_t)jv[r] * NF + l15;
            float* grow = agg + (size_t)iv[r] * NF + l15;
            #pragma unroll
            for (int t = 0; t < 8; ++t) {
                float w2 = sspf_fast(acc2[t][r] + b2r[t]) * c;
                atomicAdd(grow + t * 16, hrow[t * 16] * w2);
            }
        }
    }
}

extern "C" void kernel_launch(void* const* d_in, const int* in_sizes, int n_in,
                              void* d_out, int out_size, void* d_ws, size_t ws_size,
                              hipStream_t stream) {
    const float* x     = (const float*)d_in[0];
    const float* r_ij  = (const float*)d_in[1];
    const float* f_ij  = (const float*)d_in[2];
    const int*   ind_i = (const int*)d_in[3];
    const int*   ind_j = (const int*)d_in[4];
    const float* Wf1   = (const float*)d_in[5];
    const float* bf1   = (const float*)d_in[6];
    const float* Wf2   = (const float*)d_in[7];
    const float* bf2   = (const float*)d_in[8];
    const float* Win   = (const float*)d_in[9];
    const float* Wout  = (const float*)d_in[10];
    const float* bout  = (const float*)d_in[11];
    float* out = (float*)d_out;

    float*  agg  = (float*)d_ws;                          // [N][128] f32
    float*  h    = agg + (size_t)N_ATOMS * NF;            // [N][128] f32
    half_t* w1t  = (half_t*)(h + (size_t)N_ATOMS * NF);   // [128][64] f16
    half_t* w2t  = w1t + 128 * 64;                        // [128][128] f16

    (void)hipMemsetAsync(agg, 0, (size_t)N_ATOMS * NF * sizeof(float), stream);

    preconv_kernel<<<96, 256, 0, stream>>>(Wf1, Wf2, w1t, w2t);

    const int gemm_blocks = (N_ATOMS + 31) / 32;
    gemm128_kernel<false><<<gemm_blocks, 256, 0, stream>>>(x, Win, nullptr, h, N_ATOMS);

    edge_kernel<<<N_EDGES / EPB, 256, 0, stream>>>(f_ij, r_ij, ind_i, ind_j,
                                                   w1t, w2t, bf1, bf2, h, agg);

    gemm128_kernel<true><<<gemm_blocks, 256, 0, stream>>>(agg, Wout, bout, out, N_ATOMS);
}

// Round 5
// 811.796 us; speedup vs baseline: 2.6970x; 1.2448x over previous
//
#include <hip/hip_runtime.h>
#include <math.h>

#define N_ATOMS 50000
#define N_EDGES 1600000
#define NF 128
#define NG 50
#define ITERS 4
#define EPB 512            // edges per block (8 waves x 16 edges x 4 iters)
#define LOG2F_ 0.69314718055994530942f
#define PI_OVER_CUT 0.31415926535897932f
#define CUTOFF_F 10.0f

typedef _Float16 half_t;
typedef _Float16 f16x8 __attribute__((ext_vector_type(8)));
typedef _Float16 f16x2 __attribute__((ext_vector_type(2)));
typedef float f32x4 __attribute__((ext_vector_type(4)));
typedef unsigned int u32x4 __attribute__((ext_vector_type(4)));

__device__ __forceinline__ float sspf_fast(float x) {
    float e = __expf(-fabsf(x));
    float l = __logf(1.0f + e);
    return fmaxf(x, 0.0f) + (l - LOG2F_);
}

__device__ __forceinline__ unsigned short f2h_bits(float x) {
    half_t h = (half_t)x;
    return __builtin_bit_cast(unsigned short, h);
}

// ---------------- fp32 node GEMM (unchanged) ----------------
template <bool BIAS_SSP>
__global__ __launch_bounds__(256) void gemm128_kernel(
    const float* __restrict__ X, const float* __restrict__ W,
    const float* __restrict__ bias, float* __restrict__ Y, int N) {
    __shared__ float xs[32][128];
    const int row0 = blockIdx.x * 32;
    const int tid = threadIdx.x;
    {
        const float4* src = (const float4*)(X + (size_t)row0 * 128);
        float4* dst = (float4*)(&xs[0][0]);
        for (int i = tid; i < 32 * 32; i += 256) {
            int r = i >> 5;
            float4 v = {0.f, 0.f, 0.f, 0.f};
            if (row0 + r < N) v = src[i];
            dst[i] = v;
        }
    }
    __syncthreads();

    const int rq = tid >> 5;
    const int cq = tid & 31;
    float4 a0 = {0,0,0,0}, a1 = {0,0,0,0}, a2 = {0,0,0,0}, a3 = {0,0,0,0};
    const float4* Wv = (const float4*)W;

    #pragma unroll 4
    for (int k = 0; k < 128; ++k) {
        float4 w = Wv[k * 32 + cq];
        float x0 = xs[rq * 4 + 0][k];
        float x1 = xs[rq * 4 + 1][k];
        float x2 = xs[rq * 4 + 2][k];
        float x3 = xs[rq * 4 + 3][k];
        a0.x += x0 * w.x; a0.y += x0 * w.y; a0.z += x0 * w.z; a0.w += x0 * w.w;
        a1.x += x1 * w.x; a1.y += x1 * w.y; a1.z += x1 * w.z; a1.w += x1 * w.w;
        a2.x += x2 * w.x; a2.y += x2 * w.y; a2.z += x2 * w.z; a2.w += x2 * w.w;
        a3.x += x3 * w.x; a3.y += x3 * w.y; a3.z += x3 * w.z; a3.w += x3 * w.w;
    }

    float4 bq = {0,0,0,0};
    if (BIAS_SSP) bq = ((const float4*)bias)[cq];
    #pragma unroll
    for (int i = 0; i < 4; ++i) {
        float4 v = (i == 0) ? a0 : (i == 1) ? a1 : (i == 2) ? a2 : a3;
        int r = row0 + rq * 4 + i;
        if (r >= N) continue;
        if (BIAS_SSP) {
            v.x = sspf_fast(v.x + bq.x); v.y = sspf_fast(v.y + bq.y);
            v.z = sspf_fast(v.z + bq.z); v.w = sspf_fast(v.w + bq.w);
        }
        ((float4*)(Y + (size_t)r * 128))[cq] = v;
    }
}

// ---------------- weight pre-convert: f32 -> f16, transposed ----------------
__global__ __launch_bounds__(256) void preconv_kernel(
    const float* __restrict__ Wf1, const float* __restrict__ Wf2,
    half_t* __restrict__ w1t, half_t* __restrict__ w2t) {
    int id = blockIdx.x * 256 + threadIdx.x;
    if (id < 128 * 64) {
        int col = id >> 6, k = id & 63;
        w1t[id] = (k < NG) ? (half_t)Wf1[k * NF + col] : (half_t)0.0f;
    } else if (id < 128 * 64 + 128 * 128) {
        int t = id - 128 * 64;
        int col = t >> 7, k = t & 127;
        w2t[t] = (half_t)Wf2[k * NF + col];
    }
}

// LDS: [0,16384) W1T swz | [16384,49152) W2T swz | [49152,81920) 8x4KB W1OUT
#define OFF_W2T   16384
#define OFF_W1OUT 49152

__global__ __launch_bounds__(512) void edge_kernel(
    const float* __restrict__ f_ij, const float* __restrict__ r_ij,
    const int* __restrict__ ind_i, const int* __restrict__ ind_j,
    const half_t* __restrict__ w1t_g, const half_t* __restrict__ w2t_g,
    const float* __restrict__ bf1, const float* __restrict__ bf2,
    const float* __restrict__ h, float* __restrict__ agg) {
    __shared__ __align__(16) unsigned char lds[81920];
    const int tid = threadIdx.x;

    // ---- stage weights once per block ----
    for (int c = tid; c < 1024; c += 512) {
        int col = c >> 3, kc = c & 7;
        u32x4 v = ((const u32x4*)w1t_g)[c];
        *(u32x4*)(lds + (col << 7) + ((kc ^ (col & 7)) << 4)) = v;
    }
    for (int c = tid; c < 2048; c += 512) {
        int col = c >> 4, kc = c & 15;
        u32x4 v = ((const u32x4*)w2t_g)[c];
        int slot = (kc & 8) | ((kc & 7) ^ (col & 7));
        *(u32x4*)(lds + OFF_W2T + (col << 8) + (slot << 4)) = v;
    }

    const int lane = tid & 63;
    const int wid = tid >> 6;          // 0..7
    const int l15 = lane & 15;
    const int lg  = lane >> 4;
    const int l7  = lane & 7;
    const int h3  = l15 >> 3;
    const int hb  = (l7 >> 2) & 1;
    const int lgl = lg ^ (l7 & 3);

    float b1r[8], b2r[8];
    #pragma unroll
    for (int t = 0; t < 8; ++t) {
        b1r[t] = bf1[t * 16 + l15];
        b2r[t] = bf2[t * 16 + l15];
    }

    const int b1b0 = (l15 << 7) + (hb << 6) + (lgl << 4);
    const int b1b1 = (l15 << 7) + ((hb ^ 1) << 6) + (lgl << 4);
    const int b2b0 = OFF_W2T + (l15 << 8) + (hb << 6) + (lgl << 4);
    const int b2b1 = OFF_W2T + (l15 << 8) + ((hb ^ 1) << 6) + (lgl << 4);
    const int a2b0 = OFF_W1OUT + wid * 4096 + (l15 << 8) + (hb << 6) + (lgl << 4);
    const int a2b1 = OFF_W1OUT + wid * 4096 + (l15 << 8) + ((hb ^ 1) << 6) + (lgl << 4);
    const int ep1base = OFF_W1OUT + wid * 4096 + lg * 1024 + l7 * 2;
    const int rw4 = (lg & 1) * 4;

    const int bb = blockIdx.x * EPB;
    const float* aptr = f_ij + (size_t)(bb + wid * 16 + l15) * NG + lg * 8;

    __syncthreads();

    for (int it = 0; it < ITERS; ++it) {
        const int eb = bb + it * 128 + wid * 16;

        // ---- A fragments: global -> registers ----
        float2 q[8];
        #pragma unroll
        for (int p = 0; p < 4; ++p) q[p] = *(const float2*)(aptr + 2 * p);
        #pragma unroll
        for (int p = 0; p < 4; ++p) {
            float2 v = {0.f, 0.f};
            if (lg * 8 + 2 * p <= 16) v = *(const float2*)(aptr + 32 + 2 * p);
            q[4 + p] = v;
        }
        f16x8 a1[2];
        #pragma unroll
        for (int ks = 0; ks < 2; ++ks) {
            #pragma unroll
            for (int p = 0; p < 4; ++p) {
                f16x2 hv = __builtin_bit_cast(f16x2,
                    __builtin_amdgcn_cvt_pkrtz(q[ks * 4 + p].x, q[ks * 4 + p].y));
                a1[ks][2 * p]     = hv[0];
                a1[ks][2 * p + 1] = hv[1];
            }
        }
        aptr += (size_t)128 * NG;

        // ---- GEMM1 ----
        f32x4 acc1[8];
        #pragma unroll
        for (int t = 0; t < 8; ++t) acc1[t] = (f32x4){0.f, 0.f, 0.f, 0.f};
        #pragma unroll
        for (int t = 0; t < 8; ++t) {
            f16x8 b0 = *(const f16x8*)(lds + b1b0 + t * 2048);
            f16x8 b1 = *(const f16x8*)(lds + b1b1 + t * 2048);
            acc1[t] = __builtin_amdgcn_mfma_f32_16x16x32_f16(a1[0], b0, acc1[t], 0, 0, 0);
            acc1[t] = __builtin_amdgcn_mfma_f32_16x16x32_f16(a1[1], b1, acc1[t], 0, 0, 0);
        }

        // ---- epilogue1: ssp -> f16 -> per-wave W1OUT ----
        #pragma unroll
        for (int t = 0; t < 8; ++t) {
            #pragma unroll
            for (int r = 0; r < 4; ++r) {
                unsigned short bits = f2h_bits(sspf_fast(acc1[t][r] + b1r[t]));
                int slotx = (2 * (t & 3) + h3) ^ (rw4 + r);
                *(unsigned short*)(lds + ep1base + r * 256 + ((t >> 2) << 7) + (slotx << 4)) = bits;
            }
        }

        // ---- GEMM2 ----
        f32x4 acc2[8];
        #pragma unroll
        for (int t = 0; t < 8; ++t) acc2[t] = (f32x4){0.f, 0.f, 0.f, 0.f};
        f16x8 a2[4];
        #pragma unroll
        for (int ks = 0; ks < 4; ++ks) {
            int addr = ((ks & 1) ? a2b1 : a2b0) + (ks >> 1) * 128;
            a2[ks] = *(const f16x8*)(lds + addr);
        }
        #pragma unroll
        for (int t = 0; t < 8; ++t) {
            #pragma unroll
            for (int ks = 0; ks < 4; ++ks) {
                int addr = ((ks & 1) ? b2b1 : b2b0) + (ks >> 1) * 128 + t * 4096;
                f16x8 b = *(const f16x8*)(lds + addr);
                acc2[t] = __builtin_amdgcn_mfma_f32_16x16x32_f16(a2[ks], b, acc2[t], 0, 0, 0);
            }
        }

        // ---- epilogue2 ----
        const int erow = eb + lg * 4;
        float rv[4]; int jv[4], iv[4];
        #pragma unroll
        for (int r = 0; r < 4; ++r) {
            rv[r] = r_ij[erow + r];
            jv[r] = ind_j[erow + r];
            iv[r] = ind_i[erow + r];
        }
        #pragma unroll
        for (int r = 0; r < 4; ++r) {
            float c = 0.5f * (__cosf(rv[r] * PI_OVER_CUT) + 1.0f);
            c = (rv[r] < CUTOFF_F) ? c : 0.0f;
            const float* hrow = h + (size_t)jv[r] * NF + l15;
            float* grow = agg + (size_t)iv[r] * NF + l15;
            #pragma unroll
            for (int t = 0; t < 8; ++t) {
                float w2 = sspf_fast(acc2[t][r] + b2r[t]) * c;
                atomicAdd(grow + t * 16, hrow[t * 16] * w2);
            }
        }
    }
}

extern "C" void kernel_launch(void* const* d_in, const int* in_sizes, int n_in,
                              void* d_out, int out_size, void* d_ws, size_t ws_size,
                              hipStream_t stream) {
    const float* x     = (const float*)d_in[0];
    const float* r_ij  = (const float*)d_in[1];
    const float* f_ij  = (const float*)d_in[2];
    const int*   ind_i = (const int*)d_in[3];
    const int*   ind_j = (const int*)d_in[4];
    const float* Wf1   = (const float*)d_in[5];
    const float* bf1   = (const float*)d_in[6];
    const float* Wf2   = (const float*)d_in[7];
    const float* bf2   = (const float*)d_in[8];
    const float* Win   = (const float*)d_in[9];
    const float* Wout  = (const float*)d_in[10];
    const float* bout  = (const float*)d_in[11];
    float* out = (float*)d_out;

    float*  agg  = (float*)d_ws;
    float*  h    = agg + (size_t)N_ATOMS * NF;
    half_t* w1t  = (half_t*)(h + (size_t)N_ATOMS * NF);
    half_t* w2t  = w1t + 128 * 64;

    (void)hipMemsetAsync(agg, 0, (size_t)N_ATOMS * NF * sizeof(float), stream);

    preconv_kernel<<<96, 256, 0, stream>>>(Wf1, Wf2, w1t, w2t);

    const int gemm_blocks = (N_ATOMS + 31) / 32;
    gemm128_kernel<false><<<gemm_blocks, 256, 0, stream>>>(x, Win, nullptr, h, N_ATOMS);

    edge_kernel<<<N_EDGES / EPB, 512, 0, stream>>>(f_ij, r_ij, ind_i, ind_j,
                                                   w1t, w2t, bf1, bf2, h, agg);

    gemm128_kernel<true><<<gemm_blocks, 256, 0, stream>>>(agg, Wout, bout, out, N_ATOMS);
}